// Round 1
// baseline (1411.828 us; speedup 1.0000x reference)
//
#include <hip/hip_runtime.h>

// PaiNN update, fused single kernel, bf16 MFMA (16x16x32), fp32 accumulate.
// Round 3: tile pipelining. Each block processes TPB=5 consecutive 16-node
// tiles with double-buffered staging: next tile's global loads are issued
// before GEMM1 (HBM latency hides under GEMM1+GEMM2), converted+written to
// the alternate LDS buffer between GEMM2 and the second barrier. 2 barriers
// per tile (was 3 + one stage drain per block). GEMM3+epilogue overlaps the
// next tile's prefetch+GEMM1 with no intervening barrier.
// LDS 43.5 KB -> 3 blocks/CU; latency hiding now intra-block, not occupancy.

#define NT 16
#define TPB 5            // tiles per block; 200000 = 2500 blocks * 5 * 16
#define STRA 136         // smA row stride in bf16 (128 + 8 pad)
#define STRS 136
#define STRN 136
#define STRH 136

typedef __attribute__((ext_vector_type(8))) short bf16x8;
typedef __attribute__((ext_vector_type(4))) short short4v;
typedef __attribute__((ext_vector_type(4))) float f32x4;

#define MFMA16(a, b, c) __builtin_amdgcn_mfma_f32_16x16x32_bf16(a, b, c, 0, 0, 0)

__device__ __forceinline__ short f2bf(float x) {
    union { float f; unsigned u; } v; v.f = x;
    unsigned r = v.u + 0x7fffu + ((v.u >> 16) & 1u);   // round-to-nearest-even
    return (short)(r >> 16);
}

// Transpose + fp32->bf16 all weights into ws (K-contiguous per output column):
//   Ut  [g=0..127][k=0..127]  at ws + 0
//   Vt  [g=0..127][k=0..127]  at ws + 16384
//   M1t [g=0..127][k=0..255]  at ws + 32768
//   M2t [g=0..383][k=0..127]  at ws + 65536      (total 114688 shorts = 224 KB)
__global__ void prep_weights(const float* __restrict__ Uw, const float* __restrict__ Vw,
                             const float* __restrict__ m1w, const float* __restrict__ m2w,
                             short* __restrict__ ws) {
    int idx = blockIdx.x * 256 + threadIdx.x;
    if (idx < 16384) {
        int g = idx >> 7, k = idx & 127;
        ws[idx]         = f2bf(Uw[k * 128 + g]);
        ws[16384 + idx] = f2bf(Vw[k * 128 + g]);
    } else if (idx < 49152) {
        int j = idx - 16384;           // m1_w is (256,128): out[g][k] = in[k][g]
        int g = j >> 8, k = j & 255;
        ws[32768 + j] = f2bf(m1w[k * 128 + g]);
    } else if (idx < 98304) {
        int j = idx - 49152;           // m2_w is (128,384): out[g][k] = in[k][g]
        int g = j >> 7, k = j & 127;
        ws[65536 + j] = f2bf(m2w[k * 384 + g]);
    }
}

__global__ __launch_bounds__(256, 3)
void painn_fused(const float* __restrict__ nf,
                 const float* __restrict__ Ub, const float* __restrict__ Vb,
                 const float* __restrict__ m1b, const float* __restrict__ m2b,
                 const short* __restrict__ wbuf,
                 float* __restrict__ out) {
    extern __shared__ short lds[];
    short* smA0 = lds;                  // [48][STRA] staging buf 0 (vector part)
    short* smS0 = smA0 + 48 * STRA;     // [16][STRS] staging buf 0 (scalar part)
    short* smA1 = smS0 + 16 * STRS;     // staging buf 1
    short* smS1 = smA1 + 48 * STRA;
    short* smN  = smS1 + 16 * STRS;     // [16][STRN] Vv_norm half of mlp_in
    short* smH  = smN  + 16 * STRN;     // [16][STRH] h (post-silu)

    const short* Ut  = wbuf;
    const short* Vt  = wbuf + 16384;
    const short* M1t = wbuf + 32768;
    const short* M2t = wbuf + 65536;

    const int tid  = threadIdx.x;
    const int wave = tid >> 6;
    const int lane = tid & 63;
    const int fc   = lane & 15;       // MFMA col within 16-tile (C/D: col = lane&15)
    const int quad = lane >> 4;       // C/D: row = quad*4 + reg ; A/B: k = quad*8 + j
    const int ntg0 = wave * 2;        // this wave's first global N-tile (of 16 cols)

    // ---- tile-invariant per-lane biases (hoisted out of the tile loop) ----
    float ub_[2], vb_[2], m1b_[2], bvv_[2], bsv_[2], bss_[2];
    #pragma unroll
    for (int nt = 0; nt < 2; ++nt) {
        const int g = (ntg0 + nt) * 16 + fc;
        ub_[nt]  = Ub[g];  vb_[nt]  = Vb[g];  m1b_[nt] = m1b[g];
        bvv_[nt] = m2b[g]; bsv_[nt] = m2b[128 + g]; bss_[nt] = m2b[256 + g];
    }

    // ---- staging geometry (fixed per thread) ----
    // chunk = tid + 256*it  ->  node row n = (tid>>7) + 2*it, float col = (tid&127)*4
    const int colf = (tid & 127) << 2;
    const int rowb = tid >> 7;           // 0 or 1
    const bool isS = colf < 128;
    const int cA = (colf - 128) >> 7;    // only meaningful when !isS
    const int kA = (colf - 128) & 127;

    const long nodebase0 = (long)blockIdx.x * (TPB * NT);

    float4 v[8];

    // ---------------- prologue: stage tile 0 -> buffer 0 ----------------
    {
        const float* src = nf + nodebase0 * 512;
        #pragma unroll
        for (int it = 0; it < 8; ++it)
            v[it] = *(const float4*)(src + (long)(rowb + 2 * it) * 512 + colf);
        #pragma unroll
        for (int it = 0; it < 8; ++it) {
            const int n = rowb + 2 * it;
            short4v s;
            s.x = f2bf(v[it].x); s.y = f2bf(v[it].y);
            s.z = f2bf(v[it].z); s.w = f2bf(v[it].w);
            if (isS) *(short4v*)&smS0[n * STRS + colf] = s;
            else     *(short4v*)&smA0[(cA * 16 + n) * STRA + kA] = s;
        }
    }
    __syncthreads();

    short* sA = smA0; short* sS = smS0;   // compute buffers (tile t)
    short* dA = smA1; short* dS = smS1;   // staging target (tile t+1)

    #pragma unroll 1
    for (int t = 0; t < TPB; ++t) {
        const long nodebase = nodebase0 + (long)t * NT;

        // ---- issue next-tile prefetch (results used only after GEMM2) ----
        if (t + 1 < TPB) {
            const float* src = nf + (nodebase + NT) * 512;
            #pragma unroll
            for (int it = 0; it < 8; ++it)
                v[it] = *(const float4*)(src + (long)(rowb + 2 * it) * 512 + colf);
            __builtin_amdgcn_sched_barrier(0);   // pin loads before GEMM1
        }

        // ---------------- GEMM1: Uv, Vv = nv @ {U_w, V_w} ----------------
        f32x4 accU[2][3], accV[2][3];
        #pragma unroll
        for (int nt = 0; nt < 2; ++nt)
            #pragma unroll
            for (int c = 0; c < 3; ++c) { accU[nt][c] = (f32x4)(0.0f); accV[nt][c] = (f32x4)(0.0f); }

        #pragma unroll
        for (int kb = 0; kb < 4; ++kb) {
            const int koff = kb * 32 + quad * 8;
            bf16x8 af[3];
            #pragma unroll
            for (int c = 0; c < 3; ++c)
                af[c] = *(const bf16x8*)&sA[(c * 16 + fc) * STRA + koff];
            bf16x8 bu[2], bv[2];
            #pragma unroll
            for (int nt = 0; nt < 2; ++nt) {
                const int g = (ntg0 + nt) * 16 + fc;
                bu[nt] = *(const bf16x8*)&Ut[g * 128 + koff];
                bv[nt] = *(const bf16x8*)&Vt[g * 128 + koff];
            }
            #pragma unroll
            for (int nt = 0; nt < 2; ++nt)
                #pragma unroll
                for (int c = 0; c < 3; ++c) {
                    accU[nt][c] = MFMA16(af[c], bu[nt], accU[nt][c]);
                    accV[nt][c] = MFMA16(af[c], bv[nt], accV[nt][c]);
                }
        }

        // ---- epilogue 1: +bias, inner = sum_c Uv*Vv, norm -> smN ----
        float inner[2][4];
        #pragma unroll
        for (int nt = 0; nt < 2; ++nt) {
            const int g = (ntg0 + nt) * 16 + fc;
            const float ub = ub_[nt], vb = vb_[nt];
            #pragma unroll
            for (int i = 0; i < 4; ++i) {
                float u0 = accU[nt][0][i] + ub;
                float u1 = accU[nt][1][i] + ub;
                float u2 = accU[nt][2][i] + ub;
                float v0 = accV[nt][0][i] + vb;
                float v1 = accV[nt][1][i] + vb;
                float v2 = accV[nt][2][i] + vb;
                accU[nt][0][i] = u0; accU[nt][1][i] = u1; accU[nt][2][i] = u2;
                inner[nt][i] = u0 * v0 + u1 * v1 + u2 * v2;
                const float nrm = sqrtf(v0 * v0 + v1 * v1 + v2 * v2);
                const int nl = quad * 4 + i;
                smN[nl * STRN + g] = f2bf(nrm);
            }
        }
        __syncthreads();   // sync A: smN ready; prev readers of dA/dS done

        // ---------------- GEMM2: h = silu(mlp_in @ m1_w + b) ----------------
        f32x4 acc2[2];
        acc2[0] = (f32x4)(0.0f); acc2[1] = (f32x4)(0.0f);
        #pragma unroll
        for (int kb = 0; kb < 8; ++kb) {
            const int kk = (kb & 3) * 32 + quad * 8;
            bf16x8 a0 = (kb < 4) ? *(const bf16x8*)&smN[fc * STRN + kk]
                                 : *(const bf16x8*)&sS[fc * STRS + kk];
            #pragma unroll
            for (int nt = 0; nt < 2; ++nt) {
                const int g = (ntg0 + nt) * 16 + fc;
                bf16x8 b = *(const bf16x8*)&M1t[g * 256 + kb * 32 + quad * 8];
                acc2[nt] = MFMA16(a0, b, acc2[nt]);
            }
        }
        #pragma unroll
        for (int nt = 0; nt < 2; ++nt) {
            const int g = (ntg0 + nt) * 16 + fc;
            const float bb = m1b_[nt];
            #pragma unroll
            for (int i = 0; i < 4; ++i) {
                const float x = acc2[nt][i] + bb;
                const float sl = x / (1.0f + __expf(-x));
                const int nl = quad * 4 + i;
                smH[nl * STRH + g] = f2bf(sl);
            }
        }

        // ---- convert + write prefetched tile into the alternate buffer ----
        if (t + 1 < TPB) {
            #pragma unroll
            for (int it = 0; it < 8; ++it) {
                const int n = rowb + 2 * it;
                short4v s;
                s.x = f2bf(v[it].x); s.y = f2bf(v[it].y);
                s.z = f2bf(v[it].z); s.w = f2bf(v[it].w);
                if (isS) *(short4v*)&dS[n * STRS + colf] = s;
                else     *(short4v*)&dA[(cA * 16 + n) * STRA + kA] = s;
            }
        }
        __syncthreads();   // sync B: smH ready; next tile's buffers ready

        // ---------------- GEMM3: mlp_out = h @ m2_w ----------------
        f32x4 acc3[3][2];
        #pragma unroll
        for (int p = 0; p < 3; ++p) { acc3[p][0] = (f32x4)(0.0f); acc3[p][1] = (f32x4)(0.0f); }
        #pragma unroll
        for (int kb = 0; kb < 4; ++kb) {
            const int koff = kb * 32 + quad * 8;
            bf16x8 a0 = *(const bf16x8*)&smH[fc * STRH + koff];
            #pragma unroll
            for (int p = 0; p < 3; ++p)
                #pragma unroll
                for (int nt = 0; nt < 2; ++nt) {
                    const int gcol = p * 128 + (ntg0 + nt) * 16 + fc;
                    bf16x8 b = *(const bf16x8*)&M2t[gcol * 128 + koff];
                    acc3[p][nt] = MFMA16(a0, b, acc3[p][nt]);
                }
        }

        // ---------------- epilogue: residual add, write out ----------------
        // (no barrier after this: flows into next tile's prefetch + GEMM1)
        #pragma unroll
        for (int nt = 0; nt < 2; ++nt) {
            const int g = (ntg0 + nt) * 16 + fc;
            const float bvv = bvv_[nt], bsv = bsv_[nt], bss = bss_[nt];
            float nfv[4][4];
            #pragma unroll
            for (int i = 0; i < 4; ++i) {      // batch the re-reads (L2 hits)
                const long base = (nodebase + quad * 4 + i) * 512;
                nfv[i][0] = nf[base + g];
                nfv[i][1] = nf[base + 128 + g];
                nfv[i][2] = nf[base + 256 + g];
                nfv[i][3] = nf[base + 384 + g];
            }
            #pragma unroll
            for (int i = 0; i < 4; ++i) {
                const long base = (nodebase + quad * 4 + i) * 512;
                const float avv = acc3[0][nt][i] + bvv;
                const float asv = acc3[1][nt][i] + bsv;
                const float ass = acc3[2][nt][i] + bss;
                const float ds  = asv * inner[nt][i] + ass;
                out[base + g] = nfv[i][0] + ds;
                #pragma unroll
                for (int c = 0; c < 3; ++c)
                    out[base + 128 + c * 128 + g] = nfv[i][c + 1] + avv * accU[nt][c][i];
            }
        }

        // swap staging buffers
        short* tmp;
        tmp = sA; sA = dA; dA = tmp;
        tmp = sS; sS = dS; dS = tmp;
    }
}

extern "C" void kernel_launch(void* const* d_in, const int* in_sizes, int n_in,
                              void* d_out, int out_size, void* d_ws, size_t ws_size,
                              hipStream_t stream) {
    (void)in_sizes; (void)n_in; (void)out_size; (void)ws_size;
    const float* node_feat = (const float*)d_in[0];
    const float* U_w  = (const float*)d_in[1];
    const float* U_b  = (const float*)d_in[2];
    const float* V_w  = (const float*)d_in[3];
    const float* V_b  = (const float*)d_in[4];
    const float* m1_w = (const float*)d_in[5];
    const float* m1_b = (const float*)d_in[6];
    const float* m2_w = (const float*)d_in[7];
    const float* m2_b = (const float*)d_in[8];
    short* wbuf = (short*)d_ws;          // needs 224 KB of workspace

    prep_weights<<<384, 256, 0, stream>>>(U_w, V_w, m1_w, m2_w, wbuf);

    const int nblocks = 200000 / (NT * TPB);   // 2500, exact
    const size_t lds_bytes =
        (size_t)(2 * (48 * STRA + 16 * STRS) + 16 * STRN + 16 * STRH) * sizeof(short); // 43520
    painn_fused<<<nblocks, 256, lds_bytes, stream>>>(
        node_feat, U_b, V_b, m1_b, m2_b, wbuf, (float*)d_out);
}